// Round 10
// baseline (8323.015 us; speedup 1.0000x reference)
//
#include <hip/hip_runtime.h>

#define LAYERS 6
#define BB 10
#define TT 2048
#define II 128
#define HH 256
#define GPL 32            // blocks per layer
#define DEPTH 8           // ring depth (power of 2)
#define NTH 256
#define NCOL 8            // h-columns per block
#define HCSTR 524         // hc row stride: 16B-aligned rows, bank stride 12 (<=2-way staging)
#define RSTRD 52          // red row stride: 16B-aligned, 8 consecutive rows tile all 32 banks
#define SLOTU 1280        // u64 per layer-slot (10 batches x 256 cols / 2)

typedef unsigned long long u64;
typedef unsigned int u32;

struct __align__(16) Smem {
    float hc[BB][HCSTR];     // [x_t | h_below , h_own] per batch
    float red[32][RSTRD];    // [localcol*4 + plane][gate*12 + b]  (wave-private rows)
};

__device__ __forceinline__ float fsig(float x) { return 1.0f / (1.0f + __expf(-x)); }
__device__ __forceinline__ float ftanh(float x) {
    x = fminf(fmaxf(x, -15.0f), 15.0f);
    float e = __expf(2.0f * x);
    return (e - 1.0f) / (e + 1.0f);
}
__device__ __forceinline__ int ld_cnt(const int* p) {
    return __hip_atomic_load(p, __ATOMIC_RELAXED, __HIP_MEMORY_SCOPE_AGENT);
}
__device__ __forceinline__ void st_cnt(int* p, int v) {
    __hip_atomic_store(p, v, __ATOMIC_RELAXED, __HIP_MEMORY_SCOPE_AGENT);
}
__device__ __forceinline__ u64 ld_u64(const u64* p) {
    return __hip_atomic_load(p, __ATOMIC_RELAXED, __HIP_MEMORY_SCOPE_AGENT);
}
__device__ __forceinline__ void st_u64(u64* p, u64 v) {
    __hip_atomic_store(p, v, __ATOMIC_RELAXED, __HIP_MEMORY_SCOPE_AGENT);
}
__device__ __forceinline__ u32 bf16r(float v) {           // RNE float->bf16 bits
    u32 x = __float_as_uint(v);
    return (x + 0x7FFFu + ((x >> 16) & 1u)) >> 16;
}
__device__ __forceinline__ u64 packh(float he, float ho, u32 tag) {
    return ((u64)tag << 32) | ((u64)bf16r(he) << 16) | (u64)bf16r(ho);
}
__device__ __forceinline__ float2 unpackh(u64 v) {
    return make_float2(__uint_as_float(((u32)(v >> 16) & 0xFFFFu) << 16),
                       __uint_as_float(((u32)v & 0xFFFFu) << 16));
}
__device__ __forceinline__ int div10(int u) { return (int)(((unsigned)u * 6554u) >> 16); } // u<16384

template <int CTRL>
__device__ __forceinline__ float dpp_xadd(float v) {
    int t = __builtin_amdgcn_mov_dpp(__float_as_int(v), CTRL, 0xf, 0xf, true);
    return v + __int_as_float(t);
}
__device__ __forceinline__ void poll32(const int* base, int tgt, bool sleep) {
    const int lane = threadIdx.x & 63;
    const int* p = base + (lane & 31);
    for (;;) {
        int v = ld_cnt(p);
        if (__ballot((lane < 32) && (v < tgt)) == 0) break;
        if (sleep) __builtin_amdgcn_s_sleep(2);
    }
    asm volatile("" ::: "memory");
}

// CH4: 4 -> K=512 (layers 1..5), 3 -> K=384 (layer 0)
template <int CH4>
__device__ void run_layer(Smem& sm, int l, int s,
                          const float* __restrict__ x,
                          const float* __restrict__ h0,
                          const float* __restrict__ c0,
                          const float* __restrict__ Wih0,
                          const float* __restrict__ Wih,
                          const float* __restrict__ Whh,
                          const float* __restrict__ bih,
                          const float* __restrict__ bhh,
                          float* __restrict__ out,
                          int* flags, float* hring)
{
    constexpr int K = CH4 * 128;
    constexpr int F = K - HH;      // 256 or 128
    constexpr int XC = CH4 - 2;    // x-part chunks [0,XC); h-part [XC,CH4)
    const int tid  = threadIdx.x;
    const int kc   = tid & 31;
    const int rg   = tid >> 5;     // local column 0..7 (NEW mapping: rg owns 4 gates of col rg)
    const int wave = tid >> 6;
    const int wl   = tid & 63;

    const float* WihL = (F == II) ? Wih0 : (Wih + (size_t)(l - 1) * 4 * HH * HH);
    const float* WhhL = Whh + (size_t)l * 4 * HH * HH;

    // ---- persistent weight registers: wreg[gate][i4]; row = gate*HH + s*8 + rg ----
    float4 wreg[4][CH4];
    #pragma unroll
    for (int ri = 0; ri < 4; ++ri) {
        const int gr = ri * HH + s * NCOL + rg;
        #pragma unroll
        for (int i4 = 0; i4 < CH4; ++i4) {
            const int k0 = (i4 * 32 + kc) * 4;
            float tmp[4];
            #pragma unroll
            for (int c = 0; c < 4; ++c) {
                const int kk = k0 + c;
                tmp[c] = (kk < F) ? WihL[(size_t)gr * F + kk]
                                  : WhhL[(size_t)gr * HH + (kk - F)];
            }
            wreg[ri][i4] = make_float4(tmp[0], tmp[1], tmp[2], tmp[3]);
        }
    }

    // ---- gate lanes: wl<20 of each wave; (b, col-parity) -> column 2*wave+e ----
    const bool gl = (wl < 20);
    const int  gb = wl >> 1, ge = wl & 1;
    const int  gj = 2 * wave + ge;          // local col handled by this lane
    const int  gcol = s * NCOL + gj;        // global col
    float cst = 0.0f, bi[4] = {0, 0, 0, 0};
    if (gl) {
        cst = c0[((size_t)l * BB + gb) * HH + gcol];
        #pragma unroll
        for (int g = 0; g < 4; ++g)
            bi[g] = bih[l * 4 * HH + g * HH + gcol] + bhh[l * 4 * HH + g * HH + gcol];
    }

    u64* const ringu  = (u64*)(hring + (size_t)l * DEPTH * BB * HH);
    const u64* belowu = (const u64*)(hring + (size_t)(l - 1) * DEPTH * BB * HH);

    // ---- prologue: stage below(0)/x(0) into hc lower ----
    if (F == II) {
        #pragma unroll
        for (int i = 0; i < 2; ++i) {
            const int q = tid + i * NTH;
            if (q < BB * (II / 4))
                *(float4*)&sm.hc[q >> 5][(q & 31) * 4] =
                    *(const float4*)&x[((size_t)(q >> 5) * TT + 0) * II + (q & 31) * 4];
        }
    } else {
        u64 v[5];
        #pragma unroll
        for (int i = 0; i < 5; ++i) v[i] = ld_u64(belowu + tid + i * NTH);
        for (;;) {
            bool bad = false;
            #pragma unroll
            for (int i = 0; i < 5; ++i) bad |= ((u32)(v[i] >> 32) != 1u);
            if (__ballot(bad) == 0) break;
            __builtin_amdgcn_s_sleep(2);
            #pragma unroll
            for (int i = 0; i < 5; ++i) v[i] = ld_u64(belowu + tid + i * NTH);
        }
        asm volatile("" ::: "memory");
        #pragma unroll
        for (int i = 0; i < 5; ++i) {
            const int u = tid + i * NTH, cp = div10(u), b = u - 10 * cp;
            *(float2*)&sm.hc[b][2 * cp] = unpackh(v[i]);
        }
    }
    __syncthreads();

    for (int t = 0; t < TT; ++t) {
        // ---- A0: issue everything global (own gather, below gather, bp flag) ----
        u64 cv[5], bv[5];
        const u64* ownslot = ringu + (size_t)((t - 1) & (DEPTH - 1)) * SLOTU;
        if (t > 0) {
            #pragma unroll
            for (int i = 0; i < 5; ++i) cv[i] = ld_u64(ownslot + tid + i * NTH);
        } else {
            const u64* hz = (const u64*)(h0 + (size_t)l * BB * HH);
            #pragma unroll
            for (int i = 0; i < 5; ++i) cv[i] = ld_u64(hz + tid + i * NTH);
        }
        const bool haveb = (F != II) && (t + 1 < TT);
        const u64* bslot = belowu + (size_t)((t + 1) & (DEPTH - 1)) * SLOTU;
        if (haveb) {
            #pragma unroll
            for (int i = 0; i < 5; ++i) bv[i] = ld_u64(bslot + tid + i * NTH);
        }
        const bool bpn = (l < LAYERS - 1) && (t >= DEPTH);
        int bp = 0x7fffffff;
        if (bpn && wl < 32) bp = ld_cnt(&flags[(l + 1) * 32 + wl]);
        if (F != II && t > 0 && tid == 64) st_cnt(&flags[l * 32 + s], t);

        // ---- x-part GEMM (masks the own-gather flight) ----
        float acc[4][BB];
        #pragma unroll
        for (int ri = 0; ri < 4; ++ri)
            #pragma unroll
            for (int b = 0; b < BB; ++b) acc[ri][b] = 0.0f;

        #pragma unroll
        for (int i4 = 0; i4 < XC; ++i4) {
            const int col = (i4 * 32 + kc) * 4;
            #pragma unroll
            for (int b = 0; b < BB; ++b) {
                const float4 h4 = *(const float4*)&sm.hc[b][col];
                #pragma unroll
                for (int ri = 0; ri < 4; ++ri) {
                    acc[ri][b] = fmaf(wreg[ri][i4].x, h4.x, acc[ri][b]);
                    acc[ri][b] = fmaf(wreg[ri][i4].y, h4.y, acc[ri][b]);
                    acc[ri][b] = fmaf(wreg[ri][i4].z, h4.z, acc[ri][b]);
                    acc[ri][b] = fmaf(wreg[ri][i4].w, h4.w, acc[ri][b]);
                }
            }
        }

        // ---- own tag-check (data IS the signal) + stage hc upper ----
        if (t > 0) {
            const u32 tg = (u32)t;
            for (;;) {
                bool bad = false;
                #pragma unroll
                for (int i = 0; i < 5; ++i) bad |= ((u32)(cv[i] >> 32) != tg);
                if (__ballot(bad) == 0) break;
                #pragma unroll
                for (int i = 0; i < 5; ++i) cv[i] = ld_u64(ownslot + tid + i * NTH);
            }
            asm volatile("" ::: "memory");
            #pragma unroll
            for (int i = 0; i < 5; ++i) {
                const int u = tid + i * NTH, cp = div10(u), b = u - 10 * cp;
                *(float2*)&sm.hc[b][F + 2 * cp] = unpackh(cv[i]);
            }
        } else {
            #pragma unroll
            for (int i = 0; i < 5; ++i) {
                const int u = tid + i * NTH, b = u >> 7, c2 = u & 127;
                union { u64 u_; float2 f; } cc; cc.u_ = cv[i];
                *(float2*)&sm.hc[b][F + 2 * c2] = cc.f;
            }
        }
        __syncthreads();   // B1: hbuf staged (also protects hc lower WAR)

        // ---- h-part GEMM ----
        #pragma unroll
        for (int i4 = XC; i4 < CH4; ++i4) {
            const int col = (i4 * 32 + kc) * 4;
            #pragma unroll
            for (int b = 0; b < BB; ++b) {
                const float4 h4 = *(const float4*)&sm.hc[b][col];
                #pragma unroll
                for (int ri = 0; ri < 4; ++ri) {
                    acc[ri][b] = fmaf(wreg[ri][i4].x, h4.x, acc[ri][b]);
                    acc[ri][b] = fmaf(wreg[ri][i4].y, h4.y, acc[ri][b]);
                    acc[ri][b] = fmaf(wreg[ri][i4].z, h4.z, acc[ri][b]);
                    acc[ri][b] = fmaf(wreg[ri][i4].w, h4.w, acc[ri][b]);
                }
            }
        }

        // ---- DPP reduce over kc bits {0,1,3}: 32 -> 4 partial planes ----
        #pragma unroll
        for (int ri = 0; ri < 4; ++ri)
            #pragma unroll
            for (int b = 0; b < BB; ++b) {
                float v = acc[ri][b];
                v = dpp_xadd<0xB1>(v);
                v = dpp_xadd<0x4E>(v);
                v = dpp_xadd<0x128>(v);
                acc[ri][b] = v;
            }

        // ---- dump planes (kc in {0,4,16,20}) into wave-private red rows ----
        if ((kc & 0x0B) == 0) {
            const int p = ((kc >> 2) & 1) | ((kc >> 3) & 2);
            float* dst = &sm.red[rg * 4 + p][0];
            #pragma unroll
            for (int ri = 0; ri < 4; ++ri) {
                *(float4*)&dst[ri * 12 + 0] =
                    make_float4(acc[ri][0], acc[ri][1], acc[ri][2], acc[ri][3]);
                *(float4*)&dst[ri * 12 + 4] =
                    make_float4(acc[ri][4], acc[ri][5], acc[ri][6], acc[ri][7]);
                *(float2*)&dst[ri * 12 + 8] = make_float2(acc[ri][8], acc[ri][9]);
            }
        }
        // NO barrier: gate lanes read only their own wave's red rows (lgkmcnt orders it)

        // ---- back-pressure (preloaded; loop only on miss) ----
        if (bpn && __ballot(bp < t - DEPTH + 1))
            poll32(&flags[(l + 1) * 32], t - DEPTH + 1, false);

        // ---- gate math + immediate publish (all 4 waves in parallel) ----
        float hout = 0.0f;
        if (gl) {
            float g4[4];
            #pragma unroll
            for (int g = 0; g < 4; ++g)
                g4[g] = ((sm.red[gj * 4 + 0][g * 12 + gb] + sm.red[gj * 4 + 1][g * 12 + gb])
                       + (sm.red[gj * 4 + 2][g * 12 + gb] + sm.red[gj * 4 + 3][g * 12 + gb]))
                       + bi[g];
            float c = fsig(g4[1]) * cst + fsig(g4[0]) * ftanh(g4[2]);
            hout = fsig(g4[3]) * ftanh(c);
            cst = c;
        }
        {   // pack (even col, odd col) via DPP xor1; even lanes store tagged u64
            int hp = __builtin_amdgcn_mov_dpp(__float_as_int(hout), 0xB1, 0xf, 0xf, true);
            if (gl && ge == 0)
                st_u64(ringu + (size_t)(t & (DEPTH - 1)) * SLOTU + (s * 4 + wave) * 10 + gb,
                       packh(hout, __int_as_float(hp), (u32)(t + 1)));
        }
        if (t == TT - 1 && gl)
            out[((size_t)l * BB + gb) * HH + gcol] = cst;

        // ---- stage below(t+1)/x(t+1) into hc lower ----
        if (haveb) {
            const u32 tg = (u32)(t + 2);
            for (;;) {
                bool bad = false;
                #pragma unroll
                for (int i = 0; i < 5; ++i) bad |= ((u32)(bv[i] >> 32) != tg);
                if (__ballot(bad) == 0) break;
                __builtin_amdgcn_s_sleep(1);
                #pragma unroll
                for (int i = 0; i < 5; ++i) bv[i] = ld_u64(bslot + tid + i * NTH);
            }
            asm volatile("" ::: "memory");
            #pragma unroll
            for (int i = 0; i < 5; ++i) {
                const int u = tid + i * NTH, cp = div10(u), b = u - 10 * cp;
                *(float2*)&sm.hc[b][2 * cp] = unpackh(bv[i]);
            }
        } else if (F == II && t + 1 < TT) {
            #pragma unroll
            for (int i = 0; i < 2; ++i) {
                const int q = tid + i * NTH;
                if (q < BB * (II / 4))
                    *(float4*)&sm.hc[q >> 5][(q & 31) * 4] =
                        *(const float4*)&x[((size_t)(q >> 5) * TT + (t + 1)) * II + (q & 31) * 4];
            }
        }
        __syncthreads();   // B3: lower(t+1) staged; upper free for next step
    }
}

__global__ __launch_bounds__(NTH, 1)
void lstm_persistent(const float* __restrict__ x, const float* __restrict__ h0,
                     const float* __restrict__ c0, const float* __restrict__ Wih0,
                     const float* __restrict__ Wih, const float* __restrict__ Whh,
                     const float* __restrict__ bih, const float* __restrict__ bhh,
                     float* __restrict__ out, int* flags, float* hring)
{
    __shared__ Smem sm;
    const int l = blockIdx.x / GPL;
    const int s = blockIdx.x % GPL;
    if (l == 0)
        run_layer<3>(sm, l, s, x, h0, c0, Wih0, Wih, Whh, bih, bhh, out, flags, hring);
    else
        run_layer<4>(sm, l, s, x, h0, c0, Wih0, Wih, Whh, bih, bhh, out, flags, hring);
}

extern "C" void kernel_launch(void* const* d_in, const int* in_sizes, int n_in,
                              void* d_out, int out_size, void* d_ws, size_t ws_size,
                              hipStream_t stream) {
    const float* x    = (const float*)d_in[0];
    const float* h0   = (const float*)d_in[1];
    const float* c0   = (const float*)d_in[2];
    const float* Wih0 = (const float*)d_in[3];
    const float* Wih  = (const float*)d_in[4];
    const float* Whh  = (const float*)d_in[5];
    const float* bih  = (const float*)d_in[6];
    const float* bhh  = (const float*)d_in[7];
    float* out  = (float*)d_out;

    int*   flags = (int*)d_ws;                        // [L][32] progress ints (one line/layer)
    float* hring = (float*)((char*)d_ws + 16384);     // [L][DEPTH] tagged u64 slots (0xAA..
                                                      // poison tag never matches any t+1)
    (void)hipMemsetAsync(d_ws, 0, 16384, stream);
    hipLaunchKernelGGL(lstm_persistent, dim3(LAYERS * GPL), dim3(NTH), 0, stream,
                       x, h0, c0, Wih0, Wih, Whh, bih, bhh, out, flags, hring);
}